// Round 1
// baseline (2697.644 us; speedup 1.0000x reference)
//
#include <hip/hip_runtime.h>

#define NN 50000
#define NE 400000
#define DIM 256
#define HID 512
#define NL 5
#define BN_EPS 1e-5f

// ---------------- setup kernels ----------------

__global__ void k_zero(int* p, int n) {
    int i = blockIdx.x * blockDim.x + threadIdx.x;
    if (i < n) p[i] = 0;
}

// C[l][a*3+b][c] = E1[l][a][c] + E2[l][b][c]   (E1 has 6 rows, E2 has 3; attrs are 0..2)
__global__ void k_ctab(const float* __restrict__ E1, const float* __restrict__ E2,
                       float* __restrict__ C) {
    int b = blockIdx.x;            // 0..44
    int l = b / 9, ab = b % 9;
    int a = ab / 3, bb = ab % 3;
    int c = threadIdx.x;
    C[(size_t)b * DIM + c] = E1[(size_t)(l * 6 + a) * DIM + c] + E2[(size_t)(l * 3 + bb) * DIM + c];
}

__global__ void k_hist(const int* __restrict__ ei, int* __restrict__ counts) {
    int e = blockIdx.x * blockDim.x + threadIdx.x;
    if (e < NE) atomicAdd(&counts[ei[NE + e]], 1);
}

// single-block exclusive scan over counts -> row_ptr (and cursor copy)
__global__ void k_scan(const int* __restrict__ counts, int* __restrict__ row_ptr,
                       int* __restrict__ cursor) {
    __shared__ int sums[1024];
    int tid = threadIdx.x;
    const int n = NN;
    int chunk = (n + 1023) / 1024;
    int start = tid * chunk;
    int end = min(start + chunk, n);
    int s = 0;
    for (int i = start; i < end; ++i) s += counts[i];
    sums[tid] = s;
    __syncthreads();
    for (int off = 1; off < 1024; off <<= 1) {
        int t = (tid >= off) ? sums[tid - off] : 0;
        __syncthreads();
        sums[tid] += t;
        __syncthreads();
    }
    int run = sums[tid] - s;   // exclusive prefix of this thread's chunk
    for (int i = start; i < end; ++i) {
        row_ptr[i] = run;
        cursor[i] = run;
        run += counts[i];
    }
    if (tid == 0) row_ptr[n] = sums[1023];
}

// pack src(20b) | attr(4b)<<20 into recs, CSR-ordered by dst
__global__ void k_fill(const int* __restrict__ ei, const int* __restrict__ ea,
                       int* __restrict__ cursor, int* __restrict__ recs) {
    int e = blockIdx.x * blockDim.x + threadIdx.x;
    if (e >= NE) return;
    int src = ei[e];
    int dst = ei[NE + e];
    int a = ea[2 * e];
    int b = ea[2 * e + 1];
    int rec = src | ((a * 3 + b) << 20);
    int pos = atomicAdd(&cursor[dst], 1);
    recs[pos] = rec;
}

// ---------------- aggregation: one wave per node ----------------
__global__ __launch_bounds__(256) void k_agg(const float* __restrict__ h,
                                             const float* __restrict__ Cl,
                                             const int* __restrict__ row_ptr,
                                             const int* __restrict__ recs,
                                             float* __restrict__ agg) {
    int node = (blockIdx.x * blockDim.x + threadIdx.x) >> 6;
    int lane = threadIdx.x & 63;
    if (node >= NN) return;
    int c = lane * 4;
    float4 self = *(const float4*)(h + (size_t)node * DIM + c);
    float4 cv0 = *(const float4*)(Cl + c);   // self-loop attr = (0,0)
    float ax = self.x + cv0.x, ay = self.y + cv0.y, az = self.z + cv0.z, aw = self.w + cv0.w;
    int e0 = row_ptr[node], e1 = row_ptr[node + 1];
    for (int e = e0; e < e1; ++e) {
        int rec = recs[e];
        int src = rec & 0xFFFFF;
        int attr = rec >> 20;
        float4 hv = *(const float4*)(h + (size_t)src * DIM + c);
        float4 cv = *(const float4*)(Cl + (size_t)attr * DIM + c);
        ax += hv.x + cv.x;
        ay += hv.y + cv.y;
        az += hv.z + cv.z;
        aw += hv.w + cv.w;
    }
    float4 o = {ax, ay, az, aw};
    *(float4*)(agg + (size_t)node * DIM + c) = o;
}

// ---------------- fp32 tiled GEMM: C = A[MxK] * B[KxN] + bias (+relu) ----------------
#define BM 128
#define BN 64
#define BK 16
template <bool RELU>
__global__ __launch_bounds__(256) void k_gemm(const float* __restrict__ A,
                                              const float* __restrict__ B,
                                              const float* __restrict__ bias,
                                              float* __restrict__ C,
                                              int M, int N, int K) {
    __shared__ float As[BK][BM + 4];
    __shared__ float Bs[BK][BN];
    int tid = threadIdx.x;
    int row0 = blockIdx.y * BM;
    int col0 = blockIdx.x * BN;
    int tx = tid & 15;   // 16 thread-cols * 4 = 64
    int ty = tid >> 4;   // 16 thread-rows * 8 = 128
    float acc[8][4] = {};
    for (int k0 = 0; k0 < K; k0 += BK) {
        // A tile: 128x16 floats, 2 float4 per thread, store transposed As[k][m]
#pragma unroll
        for (int i = 0; i < 2; ++i) {
            int id = tid * 2 + i;
            int r = id >> 2;
            int k4 = (id & 3) * 4;
            int grow = row0 + r;
            float4 v = make_float4(0.f, 0.f, 0.f, 0.f);
            if (grow < M) v = *(const float4*)(A + (size_t)grow * K + k0 + k4);
            As[k4 + 0][r] = v.x;
            As[k4 + 1][r] = v.y;
            As[k4 + 2][r] = v.z;
            As[k4 + 3][r] = v.w;
        }
        // B tile: 16x64 floats, 1 float4 per thread
        {
            int r = tid >> 4;
            int c4 = (tid & 15) * 4;
            float4 v = *(const float4*)(B + (size_t)(k0 + r) * N + col0 + c4);
            *(float4*)&Bs[r][c4] = v;
        }
        __syncthreads();
#pragma unroll
        for (int kk = 0; kk < BK; ++kk) {
            float a[8], b[4];
#pragma unroll
            for (int i = 0; i < 8; ++i) a[i] = As[kk][ty * 8 + i];
#pragma unroll
            for (int j = 0; j < 4; ++j) b[j] = Bs[kk][tx * 4 + j];
#pragma unroll
            for (int i = 0; i < 8; ++i)
#pragma unroll
                for (int j = 0; j < 4; ++j) acc[i][j] += a[i] * b[j];
        }
        __syncthreads();
    }
    float bv[4];
#pragma unroll
    for (int j = 0; j < 4; ++j) bv[j] = bias[col0 + tx * 4 + j];
#pragma unroll
    for (int i = 0; i < 8; ++i) {
        int grow = row0 + ty * 8 + i;
        if (grow < M) {
            float4 o;
            o.x = acc[i][0] + bv[0];
            o.y = acc[i][1] + bv[1];
            o.z = acc[i][2] + bv[2];
            o.w = acc[i][3] + bv[3];
            if (RELU) {
                o.x = fmaxf(o.x, 0.f);
                o.y = fmaxf(o.y, 0.f);
                o.z = fmaxf(o.z, 0.f);
                o.w = fmaxf(o.w, 0.f);
            }
            *(float4*)(C + (size_t)grow * N + col0 + tx * 4) = o;
        }
    }
}

// ---------------- BatchNorm ----------------
__global__ void k_bnstats(const float* __restrict__ z, float* __restrict__ stats) {
    int c = threadIdx.x;   // 256 channels
    int rows = (NN + gridDim.x - 1) / gridDim.x;
    int r0 = blockIdx.x * rows;
    int r1 = min(r0 + rows, NN);
    float s = 0.f, s2 = 0.f;
    for (int r = r0; r < r1; ++r) {
        float v = z[(size_t)r * DIM + c];
        s += v;
        s2 += v * v;
    }
    atomicAdd(&stats[c], s);
    atomicAdd(&stats[DIM + c], s2);
}

__global__ void k_bnfin(const float* __restrict__ stats, const float* __restrict__ gamma,
                        const float* __restrict__ beta, float* __restrict__ ss) {
    int c = threadIdx.x;
    float mu = stats[c] * (1.0f / NN);
    float var = stats[DIM + c] * (1.0f / NN) - mu * mu;
    float sc = gamma[c] / sqrtf(var + BN_EPS);
    ss[c] = sc;
    ss[DIM + c] = beta[c] - mu * sc;
}

template <bool RELU>
__global__ void k_bnapply(const float* __restrict__ z, const float* __restrict__ ss,
                          float* __restrict__ out) {
    int i = blockIdx.x * blockDim.x + threadIdx.x;   // float4 index
    if (i >= NN * DIM / 4) return;
    int c4 = (i & (DIM / 4 - 1)) * 4;
    float4 v = ((const float4*)z)[i];
    float s0 = ss[c4], s1 = ss[c4 + 1], s2 = ss[c4 + 2], s3 = ss[c4 + 3];
    float h0 = ss[DIM + c4], h1 = ss[DIM + c4 + 1], h2 = ss[DIM + c4 + 2], h3 = ss[DIM + c4 + 3];
    v.x = v.x * s0 + h0;
    v.y = v.y * s1 + h1;
    v.z = v.z * s2 + h2;
    v.w = v.w * s3 + h3;
    if (RELU) {
        v.x = fmaxf(v.x, 0.f);
        v.y = fmaxf(v.y, 0.f);
        v.z = fmaxf(v.z, 0.f);
        v.w = fmaxf(v.w, 0.f);
    }
    ((float4*)out)[i] = v;
}

// ---------------- host launcher ----------------
extern "C" void kernel_launch(void* const* d_in, const int* in_sizes, int n_in,
                              void* d_out, int out_size, void* d_ws, size_t ws_size,
                              hipStream_t stream) {
    const float* x = (const float*)d_in[0];
    const int* ei = (const int*)d_in[1];
    const int* ea = (const int*)d_in[2];
    // d_in[3] = batch (unused: graphs are equal-sized, output = h flat)
    const float* W1 = (const float*)d_in[4];
    const float* b1 = (const float*)d_in[5];
    const float* W2 = (const float*)d_in[6];
    const float* b2 = (const float*)d_in[7];
    const float* E1 = (const float*)d_in[8];
    const float* E2 = (const float*)d_in[9];
    const float* gamma = (const float*)d_in[10];
    const float* beta = (const float*)d_in[11];
    float* out = (float*)d_out;

    char* w = (char*)d_ws;
    float* h = (float*)w;       w += (size_t)NN * DIM * 4;
    float* agg = (float*)w;     w += (size_t)NN * DIM * 4;
    float* hid = (float*)w;     w += (size_t)NN * HID * 4;
    float* Ctab = (float*)w;    w += (size_t)NL * 9 * DIM * 4;
    int* row_ptr = (int*)w;     w += (size_t)(NN + 2) * 4;
    int* counts = (int*)w;      w += (size_t)NN * 4;
    int* cursor = (int*)w;      w += (size_t)NN * 4;
    int* recs = (int*)w;        w += (size_t)NE * 4;
    float* stats = (float*)w;   w += 2 * DIM * 4;
    float* ss = (float*)w;      w += 2 * DIM * 4;

    // setup: edge-combo tables + CSR by dst
    k_zero<<<(NN + 255) / 256, 256, 0, stream>>>(counts, NN);
    k_ctab<<<NL * 9, 256, 0, stream>>>(E1, E2, Ctab);
    k_hist<<<(NE + 255) / 256, 256, 0, stream>>>(ei, counts);
    k_scan<<<1, 1024, 0, stream>>>(counts, row_ptr, cursor);
    k_fill<<<(NE + 255) / 256, 256, 0, stream>>>(ei, ea, cursor, recs);

    const float* hin = x;
    for (int l = 0; l < NL; ++l) {
        k_agg<<<(NN + 3) / 4, 256, 0, stream>>>(hin, Ctab + (size_t)l * 9 * DIM, row_ptr, recs, agg);

        dim3 g1(HID / BN, (NN + BM - 1) / BM);
        k_gemm<true><<<g1, 256, 0, stream>>>(agg, W1 + (size_t)l * DIM * HID, b1 + (size_t)l * HID,
                                             hid, NN, HID, DIM);
        dim3 g2(DIM / BN, (NN + BM - 1) / BM);
        k_gemm<false><<<g2, 256, 0, stream>>>(hid, W2 + (size_t)l * HID * DIM, b2 + (size_t)l * DIM,
                                              agg, NN, DIM, HID);

        k_zero<<<2, 256, 0, stream>>>((int*)stats, 2 * DIM);
        k_bnstats<<<512, 256, 0, stream>>>(agg, stats);
        k_bnfin<<<1, 256, 0, stream>>>(stats, gamma + (size_t)l * DIM, beta + (size_t)l * DIM, ss);

        float* hout = (l == NL - 1) ? out : h;
        int nb = (NN * DIM / 4 + 255) / 256;
        if (l < NL - 1)
            k_bnapply<true><<<nb, 256, 0, stream>>>(agg, ss, hout);
        else
            k_bnapply<false><<<nb, 256, 0, stream>>>(agg, ss, hout);
        hin = h;
    }
}

// Round 2
// 1344.939 us; speedup vs baseline: 2.0058x; 2.0058x over previous
//
#include <hip/hip_runtime.h>

#define NN 50000
#define NE 400000
#define DIM 256
#define HID 512
#define NL 5
#define BN_EPS 1e-5f

typedef float float4v __attribute__((ext_vector_type(4)));
typedef _Float16 half8 __attribute__((ext_vector_type(8)));
typedef _Float16 half4v __attribute__((ext_vector_type(4)));

__device__ __forceinline__ void gl_lds16(const void* g, void* l) {
    __builtin_amdgcn_global_load_lds((__attribute__((address_space(1))) void*)g,
                                     (__attribute__((address_space(3))) void*)l, 16, 0, 0);
}

// ---------------- setup kernels ----------------

__global__ void k_zero(int* p, int n) {
    int i = blockIdx.x * blockDim.x + threadIdx.x;
    if (i < n) p[i] = 0;
}

// C[l][a*3+b][c] = E1[l][a][c] + E2[l][b][c]
__global__ void k_ctab(const float* __restrict__ E1, const float* __restrict__ E2,
                       float* __restrict__ C) {
    int b = blockIdx.x;            // 0..44
    int l = b / 9, ab = b % 9;
    int a = ab / 3, bb = ab % 3;
    int c = threadIdx.x;
    C[(size_t)b * DIM + c] = E1[(size_t)(l * 6 + a) * DIM + c] + E2[(size_t)(l * 3 + bb) * DIM + c];
}

__global__ void k_hist(const int* __restrict__ ei, int* __restrict__ counts) {
    int e = blockIdx.x * blockDim.x + threadIdx.x;
    if (e < NE) atomicAdd(&counts[ei[NE + e]], 1);
}

__global__ void k_scan(const int* __restrict__ counts, int* __restrict__ row_ptr,
                       int* __restrict__ cursor) {
    __shared__ int sums[1024];
    int tid = threadIdx.x;
    const int n = NN;
    int chunk = (n + 1023) / 1024;
    int start = tid * chunk;
    int end = min(start + chunk, n);
    int s = 0;
    for (int i = start; i < end; ++i) s += counts[i];
    sums[tid] = s;
    __syncthreads();
    for (int off = 1; off < 1024; off <<= 1) {
        int t = (tid >= off) ? sums[tid - off] : 0;
        __syncthreads();
        sums[tid] += t;
        __syncthreads();
    }
    int run = sums[tid] - s;
    for (int i = start; i < end; ++i) {
        row_ptr[i] = run;
        cursor[i] = run;
        run += counts[i];
    }
    if (tid == 0) row_ptr[n] = sums[1023];
}

__global__ void k_fill(const int* __restrict__ ei, const int* __restrict__ ea,
                       int* __restrict__ cursor, int* __restrict__ recs) {
    int e = blockIdx.x * blockDim.x + threadIdx.x;
    if (e >= NE) return;
    int src = ei[e];
    int dst = ei[NE + e];
    int a = ea[2 * e];
    int b = ea[2 * e + 1];
    int rec = src | ((a * 3 + b) << 20);
    int pos = atomicAdd(&cursor[dst], 1);
    recs[pos] = rec;
}

// transpose + f16 convert: W [L][K][N] fp32 -> T [L][N][K] f16
__global__ void k_wt(const float* __restrict__ W, _Float16* __restrict__ T, int K, int N) {
    __shared__ float t[32][33];
    int l = blockIdx.z;
    int k0 = blockIdx.y * 32, n0 = blockIdx.x * 32;
    int tx = threadIdx.x, ty = threadIdx.y;   // (32,8)
    const float* Wl = W + (size_t)l * K * N;
    _Float16* Tl = T + (size_t)l * N * K;
    for (int d = 0; d < 32; d += 8)
        t[ty + d][tx] = Wl[(size_t)(k0 + ty + d) * N + n0 + tx];
    __syncthreads();
    for (int d = 0; d < 32; d += 8)
        Tl[(size_t)(n0 + ty + d) * K + k0 + tx] = (_Float16)t[tx][ty + d];
}

// ---------------- aggregation: one wave per node, writes f16 ----------------
__global__ __launch_bounds__(256) void k_agg(const float* __restrict__ h,
                                             const float* __restrict__ Cl,
                                             const int* __restrict__ row_ptr,
                                             const int* __restrict__ recs,
                                             _Float16* __restrict__ aggh) {
    int node = (blockIdx.x * blockDim.x + threadIdx.x) >> 6;
    int lane = threadIdx.x & 63;
    if (node >= NN) return;
    int c = lane * 4;
    float4 self = *(const float4*)(h + (size_t)node * DIM + c);
    float4 cv0 = *(const float4*)(Cl + c);
    float ax = self.x + cv0.x, ay = self.y + cv0.y, az = self.z + cv0.z, aw = self.w + cv0.w;
    int e0 = row_ptr[node], e1 = row_ptr[node + 1];
    for (int e = e0; e < e1; ++e) {
        int rec = recs[e];
        int src = rec & 0xFFFFF;
        int attr = rec >> 20;
        float4 hv = *(const float4*)(h + (size_t)src * DIM + c);
        float4 cv = *(const float4*)(Cl + (size_t)attr * DIM + c);
        ax += hv.x + cv.x;
        ay += hv.y + cv.y;
        az += hv.z + cv.z;
        aw += hv.w + cv.w;
    }
    half4v o;
    o.x = (_Float16)ax; o.y = (_Float16)ay; o.z = (_Float16)az; o.w = (_Float16)aw;
    *(half4v*)(aggh + (size_t)node * DIM + c) = o;
}

// ---------------- MFMA f16 GEMM: C = A[M][K] * Bt[N][K]^T + bias ----------------
// 128x128 tile, BK=64, 4 waves of 64x64 (4x4 frags of 16x16x32 MFMA).
// LDS rows are 128B (64 f16); 16B slots XOR-swizzled by row (slot = quad ^ (row&7))
// so ds_read_b128 frag reads are 2-way-conflict-only while global_load_lds keeps
// its mandatory contiguous lane->LDS mapping.
template <bool RELU, bool F16OUT>
__global__ __launch_bounds__(256) void k_mfma_gemm(const _Float16* __restrict__ A,
                                                   const _Float16* __restrict__ Bt,
                                                   const float* __restrict__ bias,
                                                   void* __restrict__ Cout,
                                                   int M, int N, int K) {
    __shared__ _Float16 ldsA[128 * 64];
    __shared__ _Float16 ldsB[128 * 64];
    int tid = threadIdx.x;
    int wave = tid >> 6, lane = tid & 63;
    int row0 = blockIdx.y * 128, col0 = blockIdx.x * 128;
    int wm = wave & 1, wn = wave >> 1;
    int lm = lane & 15, lg = lane >> 4;      // frag row/col and k-quad group
    int srow = lane >> 3;                    // staging: lds-row within 8-row chunk
    int sq = (lane & 7) ^ srow;              // staging: global 16B-quad for this slot

    float4v acc[4][4];
    const float4v zero = {0.f, 0.f, 0.f, 0.f};
#pragma unroll
    for (int i = 0; i < 4; ++i)
#pragma unroll
        for (int j = 0; j < 4; ++j) acc[i][j] = zero;

    for (int k0 = 0; k0 < K; k0 += 64) {
        // stage A and B tiles: 8 global_load_lds_dwordx4 per wave
#pragma unroll
        for (int j = 0; j < 4; ++j) {
            int rbase = wave * 32 + j * 8;
            int ga = row0 + rbase + srow;
            ga = min(ga, M - 1);
            gl_lds16(A + (size_t)ga * K + k0 + sq * 8, ldsA + rbase * 64);
            int gb = col0 + rbase + srow;
            gl_lds16(Bt + (size_t)gb * K + k0 + sq * 8, ldsB + rbase * 64);
        }
        __syncthreads();
#pragma unroll
        for (int kk = 0; kk < 2; ++kk) {
            half8 af[4], bf[4];
            int q = kk * 4 + lg;
#pragma unroll
            for (int mt = 0; mt < 4; ++mt) {
                int m = wm * 64 + mt * 16 + lm;
                af[mt] = *(const half8*)(ldsA + m * 64 + ((q ^ (m & 7)) * 8));
            }
#pragma unroll
            for (int nt = 0; nt < 4; ++nt) {
                int n = wn * 64 + nt * 16 + lm;
                bf[nt] = *(const half8*)(ldsB + n * 64 + ((q ^ (n & 7)) * 8));
            }
#pragma unroll
            for (int mt = 0; mt < 4; ++mt)
#pragma unroll
                for (int nt = 0; nt < 4; ++nt)
                    acc[mt][nt] = __builtin_amdgcn_mfma_f32_16x16x32_f16(af[mt], bf[nt],
                                                                         acc[mt][nt], 0, 0, 0);
        }
        __syncthreads();
    }

    // epilogue: D[row][col]: col = lane&15, row = (lane>>4)*4 + reg  (m89-verified)
#pragma unroll
    for (int nt = 0; nt < 4; ++nt) {
        int c = col0 + wn * 64 + nt * 16 + lm;
        float bv = bias[c];
#pragma unroll
        for (int mt = 0; mt < 4; ++mt) {
            int rb = row0 + wm * 64 + mt * 16 + lg * 4;
#pragma unroll
            for (int r = 0; r < 4; ++r) {
                int grow = rb + r;
                if (grow < M) {
                    float v = acc[mt][nt][r] + bv;
                    if (RELU) v = fmaxf(v, 0.f);
                    if (F16OUT)
                        ((_Float16*)Cout)[(size_t)grow * N + c] = (_Float16)v;
                    else
                        ((float*)Cout)[(size_t)grow * N + c] = v;
                }
            }
        }
    }
}

// ---------------- BatchNorm ----------------
__global__ void k_bnstats(const float* __restrict__ z, float* __restrict__ stats) {
    int c = threadIdx.x;
    int rows = (NN + gridDim.x - 1) / gridDim.x;
    int r0 = blockIdx.x * rows;
    int r1 = min(r0 + rows, NN);
    float s = 0.f, s2 = 0.f;
    for (int r = r0; r < r1; ++r) {
        float v = z[(size_t)r * DIM + c];
        s += v;
        s2 += v * v;
    }
    atomicAdd(&stats[c], s);
    atomicAdd(&stats[DIM + c], s2);
}

__global__ void k_bnfin(const float* __restrict__ stats, const float* __restrict__ gamma,
                        const float* __restrict__ beta, float* __restrict__ ss) {
    int c = threadIdx.x;
    float mu = stats[c] * (1.0f / NN);
    float var = stats[DIM + c] * (1.0f / NN) - mu * mu;
    float sc = gamma[c] / sqrtf(var + BN_EPS);
    ss[c] = sc;
    ss[DIM + c] = beta[c] - mu * sc;
}

template <bool RELU>
__global__ void k_bnapply(const float* __restrict__ z, const float* __restrict__ ss,
                          float* __restrict__ out) {
    int i = blockIdx.x * blockDim.x + threadIdx.x;
    if (i >= NN * DIM / 4) return;
    int c4 = (i & (DIM / 4 - 1)) * 4;
    float4 v = ((const float4*)z)[i];
    float s0 = ss[c4], s1 = ss[c4 + 1], s2 = ss[c4 + 2], s3 = ss[c4 + 3];
    float h0 = ss[DIM + c4], h1 = ss[DIM + c4 + 1], h2 = ss[DIM + c4 + 2], h3 = ss[DIM + c4 + 3];
    v.x = v.x * s0 + h0;
    v.y = v.y * s1 + h1;
    v.z = v.z * s2 + h2;
    v.w = v.w * s3 + h3;
    if (RELU) {
        v.x = fmaxf(v.x, 0.f);
        v.y = fmaxf(v.y, 0.f);
        v.z = fmaxf(v.z, 0.f);
        v.w = fmaxf(v.w, 0.f);
    }
    ((float4*)out)[i] = v;
}

// ---------------- host launcher ----------------
extern "C" void kernel_launch(void* const* d_in, const int* in_sizes, int n_in,
                              void* d_out, int out_size, void* d_ws, size_t ws_size,
                              hipStream_t stream) {
    const float* x = (const float*)d_in[0];
    const int* ei = (const int*)d_in[1];
    const int* ea = (const int*)d_in[2];
    const float* W1 = (const float*)d_in[4];
    const float* b1 = (const float*)d_in[5];
    const float* W2 = (const float*)d_in[6];
    const float* b2 = (const float*)d_in[7];
    const float* E1 = (const float*)d_in[8];
    const float* E2 = (const float*)d_in[9];
    const float* gamma = (const float*)d_in[10];
    const float* beta = (const float*)d_in[11];
    float* out = (float*)d_out;

    char* w = (char*)d_ws;
    float* h = (float*)w;        w += (size_t)NN * DIM * 4;        // 51.2 MB
    float* z = (float*)w;        w += (size_t)NN * DIM * 4;        // 51.2 MB
    _Float16* aggh = (_Float16*)w; w += (size_t)NN * DIM * 2;      // 25.6 MB
    _Float16* hid = (_Float16*)w;  w += (size_t)NN * HID * 2;      // 51.2 MB
    _Float16* W1t = (_Float16*)w;  w += (size_t)NL * DIM * HID * 2;
    _Float16* W2t = (_Float16*)w;  w += (size_t)NL * HID * DIM * 2;
    float* Ctab = (float*)w;     w += (size_t)NL * 9 * DIM * 4;
    float* stats = (float*)w;    w += 2 * DIM * 4;
    float* ss = (float*)w;       w += 2 * DIM * 4;
    int* row_ptr = (int*)w;      w += (size_t)(NN + 2) * 4;
    int* counts = (int*)w;       w += (size_t)NN * 4;
    int* cursor = (int*)w;       w += (size_t)NN * 4;
    int* recs = (int*)w;         w += (size_t)NE * 4;

    // setup: edge-combo tables + CSR by dst + transposed f16 weights
    k_zero<<<(NN + 255) / 256, 256, 0, stream>>>(counts, NN);
    k_ctab<<<NL * 9, 256, 0, stream>>>(E1, E2, Ctab);
    k_hist<<<(NE + 255) / 256, 256, 0, stream>>>(ei, counts);
    k_scan<<<1, 1024, 0, stream>>>(counts, row_ptr, cursor);
    k_fill<<<(NE + 255) / 256, 256, 0, stream>>>(ei, ea, cursor, recs);
    {
        dim3 b(32, 8);
        dim3 g1(HID / 32, DIM / 32, NL);   // W1: K=256 -> N=512
        k_wt<<<g1, b, 0, stream>>>(W1, W1t, DIM, HID);
        dim3 g2(DIM / 32, HID / 32, NL);   // W2: K=512 -> N=256
        k_wt<<<g2, b, 0, stream>>>(W2, W2t, HID, DIM);
    }

    const float* hin = x;
    for (int l = 0; l < NL; ++l) {
        k_agg<<<(NN + 3) / 4, 256, 0, stream>>>(hin, Ctab + (size_t)l * 9 * DIM, row_ptr, recs, aggh);

        dim3 g1(HID / 128, (NN + 127) / 128);
        k_mfma_gemm<true, true><<<g1, 256, 0, stream>>>(aggh, W1t + (size_t)l * DIM * HID,
                                                        b1 + (size_t)l * HID, hid, NN, HID, DIM);
        dim3 g2(DIM / 128, (NN + 127) / 128);
        k_mfma_gemm<false, false><<<g2, 256, 0, stream>>>(hid, W2t + (size_t)l * HID * DIM,
                                                          b2 + (size_t)l * DIM, z, NN, DIM, HID);

        k_zero<<<2, 256, 0, stream>>>((int*)stats, 2 * DIM);
        k_bnstats<<<512, 256, 0, stream>>>(z, stats);
        k_bnfin<<<1, 256, 0, stream>>>(stats, gamma + (size_t)l * DIM, beta + (size_t)l * DIM, ss);

        float* hout = (l == NL - 1) ? out : h;
        int nb = (NN * DIM / 4 + 255) / 256;
        if (l < NL - 1)
            k_bnapply<true><<<nb, 256, 0, stream>>>(z, ss, hout);
        else
            k_bnapply<false><<<nb, 256, 0, stream>>>(z, ss, hout);
        hin = h;
    }
}

// Round 3
// 996.619 us; speedup vs baseline: 2.7068x; 1.3495x over previous
//
#include <hip/hip_runtime.h>

#define NN 50000
#define NE 400000
#define DIM 256
#define HID 512
#define NL 5
#define BN_EPS 1e-5f
#define NB_SCAN 196   // ceil(NN/256)

typedef float float4v __attribute__((ext_vector_type(4)));
typedef _Float16 half8 __attribute__((ext_vector_type(8)));
typedef _Float16 half4v __attribute__((ext_vector_type(4)));

__device__ __forceinline__ void gl_lds16(const void* g, void* l) {
    __builtin_amdgcn_global_load_lds((__attribute__((address_space(1))) void*)g,
                                     (__attribute__((address_space(3))) void*)l, 16, 0, 0);
}

// ---------------- setup kernels ----------------

__global__ void k_zero(int* p, int n) {
    int i = blockIdx.x * blockDim.x + threadIdx.x;
    if (i < n) p[i] = 0;
}

__global__ void k_x2h(const float* __restrict__ x, _Float16* __restrict__ xh) {
    int i = blockIdx.x * blockDim.x + threadIdx.x;
    if (i >= NN * DIM / 4) return;
    float4 v = ((const float4*)x)[i];
    half4v o;
    o.x = (_Float16)v.x; o.y = (_Float16)v.y; o.z = (_Float16)v.z; o.w = (_Float16)v.w;
    ((half4v*)xh)[i] = o;
}

// C[l][a*3+b][c] = E1[l][a][c] + E2[l][b][c]
__global__ void k_ctab(const float* __restrict__ E1, const float* __restrict__ E2,
                       float* __restrict__ C) {
    int b = blockIdx.x;            // 0..44
    int l = b / 9, ab = b % 9;
    int a = ab / 3, bb = ab % 3;
    int c = threadIdx.x;
    C[(size_t)b * DIM + c] = E1[(size_t)(l * 6 + a) * DIM + c] + E2[(size_t)(l * 3 + bb) * DIM + c];
}

__global__ void k_hist(const int* __restrict__ ei, int* __restrict__ counts) {
    int e = blockIdx.x * blockDim.x + threadIdx.x;
    if (e < NE) atomicAdd(&counts[ei[NE + e]], 1);
}

// ---- multi-block coalesced exclusive scan of counts -> row_ptr/cursor ----
__global__ void k_bsum(const int* __restrict__ counts, int* __restrict__ bsum) {
    __shared__ int s[256];
    int t = threadIdx.x;
    int i = blockIdx.x * 256 + t;
    s[t] = (i < NN) ? counts[i] : 0;
    __syncthreads();
    for (int off = 128; off > 0; off >>= 1) {
        if (t < off) s[t] += s[t + off];
        __syncthreads();
    }
    if (t == 0) bsum[blockIdx.x] = s[0];
}

__global__ void k_bscan(const int* __restrict__ bsum, int* __restrict__ bofs) {
    __shared__ int s[256];
    int t = threadIdx.x;
    int v = (t < NB_SCAN) ? bsum[t] : 0;
    s[t] = v;
    __syncthreads();
    for (int off = 1; off < 256; off <<= 1) {
        int u = (t >= off) ? s[t - off] : 0;
        __syncthreads();
        s[t] += u;
        __syncthreads();
    }
    if (t < NB_SCAN) bofs[t] = s[t] - v;
}

__global__ void k_scatterptr(const int* __restrict__ counts, const int* __restrict__ bofs,
                             int* __restrict__ row_ptr, int* __restrict__ cursor) {
    __shared__ int s[256];
    int t = threadIdx.x;
    int i = blockIdx.x * 256 + t;
    int v = (i < NN) ? counts[i] : 0;
    s[t] = v;
    __syncthreads();
    for (int off = 1; off < 256; off <<= 1) {
        int u = (t >= off) ? s[t - off] : 0;
        __syncthreads();
        s[t] += u;
        __syncthreads();
    }
    if (i < NN) {
        int ex = bofs[blockIdx.x] + s[t] - v;
        row_ptr[i] = ex;
        cursor[i] = ex;
    }
    if (i == NN - 1) row_ptr[NN] = NE;
}

__global__ void k_fill(const int* __restrict__ ei, const int* __restrict__ ea,
                       int* __restrict__ cursor, int* __restrict__ recs) {
    int e = blockIdx.x * blockDim.x + threadIdx.x;
    if (e >= NE) return;
    int src = ei[e];
    int dst = ei[NE + e];
    int a = ea[2 * e];
    int b = ea[2 * e + 1];
    int rec = src | ((a * 3 + b) << 20);
    int pos = atomicAdd(&cursor[dst], 1);
    recs[pos] = rec;
}

// transpose + f16 convert: W [L][K][N] fp32 -> T [L][N][K] f16
__global__ void k_wt(const float* __restrict__ W, _Float16* __restrict__ T, int K, int N) {
    __shared__ float t[32][33];
    int l = blockIdx.z;
    int k0 = blockIdx.y * 32, n0 = blockIdx.x * 32;
    int tx = threadIdx.x, ty = threadIdx.y;   // (32,8)
    const float* Wl = W + (size_t)l * K * N;
    _Float16* Tl = T + (size_t)l * N * K;
    for (int d = 0; d < 32; d += 8)
        t[ty + d][tx] = Wl[(size_t)(k0 + ty + d) * N + n0 + tx];
    __syncthreads();
    for (int d = 0; d < 32; d += 8)
        Tl[(size_t)(n0 + ty + d) * K + k0 + tx] = (_Float16)t[tx][ty + d];
}

// ---------------- aggregation: one wave per node ----------------
// rows: f16 [NN][DIM]. If APPLY: row value = relu(rows*s + t) (BN affine fused).
template <bool APPLY>
__global__ __launch_bounds__(256) void k_agg(const _Float16* __restrict__ rows,
                                             const float* __restrict__ ss,
                                             const float* __restrict__ Cl,
                                             const int* __restrict__ row_ptr,
                                             const int* __restrict__ recs,
                                             _Float16* __restrict__ aggh) {
    int node = (blockIdx.x * blockDim.x + threadIdx.x) >> 6;
    int lane = threadIdx.x & 63;
    if (node >= NN) return;
    int c = lane * 4;
    float s0 = 1.f, s1 = 1.f, s2 = 1.f, s3 = 1.f, t0 = 0.f, t1 = 0.f, t2 = 0.f, t3 = 0.f;
    if (APPLY) {
        s0 = ss[c]; s1 = ss[c + 1]; s2 = ss[c + 2]; s3 = ss[c + 3];
        t0 = ss[DIM + c]; t1 = ss[DIM + c + 1]; t2 = ss[DIM + c + 2]; t3 = ss[DIM + c + 3];
    }
    float4 cv0 = *(const float4*)(Cl + c);   // self-loop attr = (0,0)
    half4v sv = *(const half4v*)(rows + (size_t)node * DIM + c);
    float ax, ay, az, aw;
    if (APPLY) {
        ax = fmaxf((float)sv.x * s0 + t0, 0.f) + cv0.x;
        ay = fmaxf((float)sv.y * s1 + t1, 0.f) + cv0.y;
        az = fmaxf((float)sv.z * s2 + t2, 0.f) + cv0.z;
        aw = fmaxf((float)sv.w * s3 + t3, 0.f) + cv0.w;
    } else {
        ax = (float)sv.x + cv0.x;
        ay = (float)sv.y + cv0.y;
        az = (float)sv.z + cv0.z;
        aw = (float)sv.w + cv0.w;
    }
    int e0 = row_ptr[node], e1 = row_ptr[node + 1];
    for (int e = e0; e < e1; ++e) {
        int rec = recs[e];
        int src = rec & 0xFFFFF;
        int attr = rec >> 20;
        half4v hv = *(const half4v*)(rows + (size_t)src * DIM + c);
        float4 cv = *(const float4*)(Cl + (size_t)attr * DIM + c);
        if (APPLY) {
            ax += fmaxf((float)hv.x * s0 + t0, 0.f) + cv.x;
            ay += fmaxf((float)hv.y * s1 + t1, 0.f) + cv.y;
            az += fmaxf((float)hv.z * s2 + t2, 0.f) + cv.z;
            aw += fmaxf((float)hv.w * s3 + t3, 0.f) + cv.w;
        } else {
            ax += (float)hv.x + cv.x;
            ay += (float)hv.y + cv.y;
            az += (float)hv.z + cv.z;
            aw += (float)hv.w + cv.w;
        }
    }
    half4v o;
    o.x = (_Float16)ax; o.y = (_Float16)ay; o.z = (_Float16)az; o.w = (_Float16)aw;
    *(half4v*)(aggh + (size_t)node * DIM + c) = o;
}

// ---------------- MFMA f16 GEMM: C = A[M][K] * Bt[N][K]^T + bias ----------------
// 128x128 tile, BK=64, 4 waves of 64x64 (4x4 frags of 16x16x32 MFMA).
// XOR-swizzled LDS (slot = quad ^ (row&7)): frag ds_read_b128 2-way only, and
// global_load_lds keeps its mandatory contiguous lane->LDS mapping.
// If STATS: also accumulate per-channel sum/sumsq of C into stats (atomics).
template <bool RELU, bool STATS>
__global__ __launch_bounds__(256) void k_mfma_gemm(const _Float16* __restrict__ A,
                                                   const _Float16* __restrict__ Bt,
                                                   const float* __restrict__ bias,
                                                   _Float16* __restrict__ Cout,
                                                   float* __restrict__ stats,
                                                   int M, int N, int K) {
    __shared__ _Float16 ldsA[128 * 64];
    __shared__ _Float16 ldsB[128 * 64];
    __shared__ float sst[2][128];
    int tid = threadIdx.x;
    int wave = tid >> 6, lane = tid & 63;
    int row0 = blockIdx.y * 128, col0 = blockIdx.x * 128;
    int wm = wave & 1, wn = wave >> 1;
    int lm = lane & 15, lg = lane >> 4;
    int srow = lane >> 3;
    int sq = (lane & 7) ^ srow;

    if (STATS && tid < 128) {
        sst[0][tid] = 0.f;
        sst[1][tid] = 0.f;
    }

    float4v acc[4][4];
    const float4v zero = {0.f, 0.f, 0.f, 0.f};
#pragma unroll
    for (int i = 0; i < 4; ++i)
#pragma unroll
        for (int j = 0; j < 4; ++j) acc[i][j] = zero;

    for (int k0 = 0; k0 < K; k0 += 64) {
#pragma unroll
        for (int j = 0; j < 4; ++j) {
            int rbase = wave * 32 + j * 8;
            int ga = row0 + rbase + srow;
            ga = min(ga, M - 1);
            gl_lds16(A + (size_t)ga * K + k0 + sq * 8, ldsA + rbase * 64);
            int gb = col0 + rbase + srow;
            gl_lds16(Bt + (size_t)gb * K + k0 + sq * 8, ldsB + rbase * 64);
        }
        __syncthreads();
#pragma unroll
        for (int kk = 0; kk < 2; ++kk) {
            half8 af[4], bf[4];
            int q = kk * 4 + lg;
#pragma unroll
            for (int mt = 0; mt < 4; ++mt) {
                int m = wm * 64 + mt * 16 + lm;
                af[mt] = *(const half8*)(ldsA + m * 64 + ((q ^ (m & 7)) * 8));
            }
#pragma unroll
            for (int nt = 0; nt < 4; ++nt) {
                int n = wn * 64 + nt * 16 + lm;
                bf[nt] = *(const half8*)(ldsB + n * 64 + ((q ^ (n & 7)) * 8));
            }
#pragma unroll
            for (int mt = 0; mt < 4; ++mt)
#pragma unroll
                for (int nt = 0; nt < 4; ++nt)
                    acc[mt][nt] = __builtin_amdgcn_mfma_f32_16x16x32_f16(af[mt], bf[nt],
                                                                         acc[mt][nt], 0, 0, 0);
        }
        __syncthreads();
    }

    // epilogue: D[row][col]: col = lane&15, row = (lane>>4)*4 + reg
    float psum[4], psq[4];
#pragma unroll
    for (int nt = 0; nt < 4; ++nt) { psum[nt] = 0.f; psq[nt] = 0.f; }
#pragma unroll
    for (int nt = 0; nt < 4; ++nt) {
        int c = col0 + wn * 64 + nt * 16 + lm;
        float bv = bias[c];
#pragma unroll
        for (int mt = 0; mt < 4; ++mt) {
            int rb = row0 + wm * 64 + mt * 16 + lg * 4;
#pragma unroll
            for (int r = 0; r < 4; ++r) {
                int grow = rb + r;
                if (grow < M) {
                    float v = acc[mt][nt][r] + bv;
                    if (RELU) v = fmaxf(v, 0.f);
                    Cout[(size_t)grow * N + c] = (_Float16)v;
                    if (STATS) {
                        psum[nt] += v;
                        psq[nt] += v * v;
                    }
                }
            }
        }
    }
    if (STATS) {
        // reduce across the 4 k-groups (lane bits 4,5) in-wave
#pragma unroll
        for (int nt = 0; nt < 4; ++nt) {
            psum[nt] += __shfl_xor(psum[nt], 16);
            psum[nt] += __shfl_xor(psum[nt], 32);
            psq[nt] += __shfl_xor(psq[nt], 16);
            psq[nt] += __shfl_xor(psq[nt], 32);
        }
        if (lg == 0) {
#pragma unroll
            for (int nt = 0; nt < 4; ++nt) {
                int ch = wn * 64 + nt * 16 + lm;
                atomicAdd(&sst[0][ch], psum[nt]);   // 2-way (wm pair) contention only
                atomicAdd(&sst[1][ch], psq[nt]);
            }
        }
        __syncthreads();
        if (tid < 128) {
            atomicAdd(&stats[col0 + tid], sst[0][tid]);
            atomicAdd(&stats[DIM + col0 + tid], sst[1][tid]);
        }
    }
}

// ---------------- BatchNorm finalize + final output ----------------
__global__ void k_bnfin(const float* __restrict__ stats, const float* __restrict__ gamma,
                        const float* __restrict__ beta, float* __restrict__ ss) {
    int c = threadIdx.x;
    float mu = stats[c] * (1.0f / NN);
    float var = stats[DIM + c] * (1.0f / NN) - mu * mu;
    float sc = gamma[c] / sqrtf(var + BN_EPS);
    ss[c] = sc;
    ss[DIM + c] = beta[c] - mu * sc;
}

__global__ void k_out(const _Float16* __restrict__ z, const float* __restrict__ ss,
                      float* __restrict__ out) {
    int i = blockIdx.x * blockDim.x + threadIdx.x;
    if (i >= NN * DIM / 4) return;
    int c4 = (i & (DIM / 4 - 1)) * 4;
    half4v v = ((const half4v*)z)[i];
    float4 o;
    o.x = (float)v.x * ss[c4] + ss[DIM + c4];
    o.y = (float)v.y * ss[c4 + 1] + ss[DIM + c4 + 1];
    o.z = (float)v.z * ss[c4 + 2] + ss[DIM + c4 + 2];
    o.w = (float)v.w * ss[c4 + 3] + ss[DIM + c4 + 3];
    ((float4*)out)[i] = o;
}

// ---------------- host launcher ----------------
extern "C" void kernel_launch(void* const* d_in, const int* in_sizes, int n_in,
                              void* d_out, int out_size, void* d_ws, size_t ws_size,
                              hipStream_t stream) {
    const float* x = (const float*)d_in[0];
    const int* ei = (const int*)d_in[1];
    const int* ea = (const int*)d_in[2];
    const float* W1 = (const float*)d_in[4];
    const float* b1 = (const float*)d_in[5];
    const float* W2 = (const float*)d_in[6];
    const float* b2 = (const float*)d_in[7];
    const float* E1 = (const float*)d_in[8];
    const float* E2 = (const float*)d_in[9];
    const float* gamma = (const float*)d_in[10];
    const float* beta = (const float*)d_in[11];
    float* out = (float*)d_out;

    char* w = (char*)d_ws;
    _Float16* xh = (_Float16*)w;   w += (size_t)NN * DIM * 2;
    _Float16* z = (_Float16*)w;    w += (size_t)NN * DIM * 2;
    _Float16* aggh = (_Float16*)w; w += (size_t)NN * DIM * 2;
    _Float16* hid = (_Float16*)w;  w += (size_t)NN * HID * 2;
    _Float16* W1t = (_Float16*)w;  w += (size_t)NL * DIM * HID * 2;
    _Float16* W2t = (_Float16*)w;  w += (size_t)NL * HID * DIM * 2;
    float* Ctab = (float*)w;       w += (size_t)NL * 9 * DIM * 4;
    float* stats = (float*)w;      w += 2 * DIM * 4;
    float* ss = (float*)w;         w += 2 * DIM * 4;
    int* row_ptr = (int*)w;        w += (size_t)(NN + 2) * 4;
    int* counts = (int*)w;         w += (size_t)NN * 4;
    int* cursor = (int*)w;         w += (size_t)NN * 4;
    int* bsum = (int*)w;           w += 256 * 4;
    int* bofs = (int*)w;           w += 256 * 4;
    int* recs = (int*)w;           w += (size_t)NE * 4;

    // setup: f16 x, edge-combo tables, CSR by dst, transposed f16 weights
    k_zero<<<(NN + 255) / 256, 256, 0, stream>>>(counts, NN);
    k_x2h<<<(NN * DIM / 4 + 255) / 256, 256, 0, stream>>>(x, xh);
    k_ctab<<<NL * 9, 256, 0, stream>>>(E1, E2, Ctab);
    k_hist<<<(NE + 255) / 256, 256, 0, stream>>>(ei, counts);
    k_bsum<<<NB_SCAN, 256, 0, stream>>>(counts, bsum);
    k_bscan<<<1, 256, 0, stream>>>(bsum, bofs);
    k_scatterptr<<<NB_SCAN, 256, 0, stream>>>(counts, bofs, row_ptr, cursor);
    k_fill<<<(NE + 255) / 256, 256, 0, stream>>>(ei, ea, cursor, recs);
    {
        dim3 b(32, 8);
        dim3 g1(HID / 32, DIM / 32, NL);
        k_wt<<<g1, b, 0, stream>>>(W1, W1t, DIM, HID);
        dim3 g2(DIM / 32, HID / 32, NL);
        k_wt<<<g2, b, 0, stream>>>(W2, W2t, HID, DIM);
    }

    for (int l = 0; l < NL; ++l) {
        const float* Cl = Ctab + (size_t)l * 9 * DIM;
        if (l == 0)
            k_agg<false><<<(NN + 3) / 4, 256, 0, stream>>>(xh, ss, Cl, row_ptr, recs, aggh);
        else
            k_agg<true><<<(NN + 3) / 4, 256, 0, stream>>>(z, ss, Cl, row_ptr, recs, aggh);

        dim3 g1(HID / 128, (NN + 127) / 128);
        k_mfma_gemm<true, false><<<g1, 256, 0, stream>>>(aggh, W1t + (size_t)l * DIM * HID,
                                                         b1 + (size_t)l * HID, hid, stats,
                                                         NN, HID, DIM);
        k_zero<<<2, 256, 0, stream>>>((int*)stats, 2 * DIM);
        dim3 g2(DIM / 128, (NN + 127) / 128);
        k_mfma_gemm<false, true><<<g2, 256, 0, stream>>>(hid, W2t + (size_t)l * HID * DIM,
                                                         b2 + (size_t)l * DIM, z, stats,
                                                         NN, DIM, HID);
        k_bnfin<<<1, 256, 0, stream>>>(stats, gamma + (size_t)l * DIM, beta + (size_t)l * DIM, ss);
    }
    k_out<<<(NN * DIM / 4 + 255) / 256, 256, 0, stream>>>(z, ss, out);
}

// Round 4
// 875.901 us; speedup vs baseline: 3.0799x; 1.1378x over previous
//
#include <hip/hip_runtime.h>

#define NN 50000
#define NE 400000
#define DIM 256
#define HID 512
#define NL 5
#define BN_EPS 1e-5f
#define NB_SCAN 196   // ceil(NN/256)

typedef float float4v __attribute__((ext_vector_type(4)));
typedef _Float16 half8 __attribute__((ext_vector_type(8)));
typedef _Float16 half4v __attribute__((ext_vector_type(4)));

__device__ __forceinline__ void gl_lds16(const void* g, void* l) {
    __builtin_amdgcn_global_load_lds((__attribute__((address_space(1))) void*)g,
                                     (__attribute__((address_space(3))) void*)l, 16, 0, 0);
}

// ---------------- setup kernels ----------------

__global__ void k_zero(int* p, int n) {
    int i = blockIdx.x * blockDim.x + threadIdx.x;
    if (i < n) p[i] = 0;
}

__global__ void k_x2h(const float* __restrict__ x, _Float16* __restrict__ xh) {
    int i = blockIdx.x * blockDim.x + threadIdx.x;
    if (i >= NN * DIM / 4) return;
    float4 v = ((const float4*)x)[i];
    half4v o;
    o.x = (_Float16)v.x; o.y = (_Float16)v.y; o.z = (_Float16)v.z; o.w = (_Float16)v.w;
    ((half4v*)xh)[i] = o;
}

// C[l][a*3+b][c] = E1[l][a][c] + E2[l][b][c]
__global__ void k_ctab(const float* __restrict__ E1, const float* __restrict__ E2,
                       float* __restrict__ C) {
    int b = blockIdx.x;            // 0..44
    int l = b / 9, ab = b % 9;
    int a = ab / 3, bb = ab % 3;
    int c = threadIdx.x;
    C[(size_t)b * DIM + c] = E1[(size_t)(l * 6 + a) * DIM + c] + E2[(size_t)(l * 3 + bb) * DIM + c];
}

__global__ void k_hist(const int* __restrict__ ei, int* __restrict__ counts) {
    int e = blockIdx.x * blockDim.x + threadIdx.x;
    if (e < NE) atomicAdd(&counts[ei[NE + e]], 1);
}

// ---- multi-block coalesced exclusive scan of counts -> row_ptr/cursor ----
__global__ void k_bsum(const int* __restrict__ counts, int* __restrict__ bsum) {
    __shared__ int s[256];
    int t = threadIdx.x;
    int i = blockIdx.x * 256 + t;
    s[t] = (i < NN) ? counts[i] : 0;
    __syncthreads();
    for (int off = 128; off > 0; off >>= 1) {
        if (t < off) s[t] += s[t + off];
        __syncthreads();
    }
    if (t == 0) bsum[blockIdx.x] = s[0];
}

__global__ void k_bscan(const int* __restrict__ bsum, int* __restrict__ bofs) {
    __shared__ int s[256];
    int t = threadIdx.x;
    int v = (t < NB_SCAN) ? bsum[t] : 0;
    s[t] = v;
    __syncthreads();
    for (int off = 1; off < 256; off <<= 1) {
        int u = (t >= off) ? s[t - off] : 0;
        __syncthreads();
        s[t] += u;
        __syncthreads();
    }
    if (t < NB_SCAN) bofs[t] = s[t] - v;
}

__global__ void k_scatterptr(const int* __restrict__ counts, const int* __restrict__ bofs,
                             int* __restrict__ row_ptr, int* __restrict__ cursor) {
    __shared__ int s[256];
    int t = threadIdx.x;
    int i = blockIdx.x * 256 + t;
    int v = (i < NN) ? counts[i] : 0;
    s[t] = v;
    __syncthreads();
    for (int off = 1; off < 256; off <<= 1) {
        int u = (t >= off) ? s[t - off] : 0;
        __syncthreads();
        s[t] += u;
        __syncthreads();
    }
    if (i < NN) {
        int ex = bofs[blockIdx.x] + s[t] - v;
        row_ptr[i] = ex;
        cursor[i] = ex;
    }
    if (i == NN - 1) row_ptr[NN] = NE;
}

__global__ void k_fill(const int* __restrict__ ei, const int* __restrict__ ea,
                       int* __restrict__ cursor, int* __restrict__ recs) {
    int e = blockIdx.x * blockDim.x + threadIdx.x;
    if (e >= NE) return;
    int src = ei[e];
    int dst = ei[NE + e];
    int a = ea[2 * e];
    int b = ea[2 * e + 1];
    int rec = src | ((a * 3 + b) << 20);
    int pos = atomicAdd(&cursor[dst], 1);
    recs[pos] = rec;
}

// transpose + f16 convert: W [L][K][N] fp32 -> T [L][N][K] f16
__global__ void k_wt(const float* __restrict__ W, _Float16* __restrict__ T, int K, int N) {
    __shared__ float t[32][33];
    int l = blockIdx.z;
    int k0 = blockIdx.y * 32, n0 = blockIdx.x * 32;
    int tx = threadIdx.x, ty = threadIdx.y;   // (32,8)
    const float* Wl = W + (size_t)l * K * N;
    _Float16* Tl = T + (size_t)l * N * K;
    for (int d = 0; d < 32; d += 8)
        t[ty + d][tx] = Wl[(size_t)(k0 + ty + d) * N + n0 + tx];
    __syncthreads();
    for (int d = 0; d < 32; d += 8)
        Tl[(size_t)(n0 + ty + d) * K + k0 + tx] = (_Float16)t[tx][ty + d];
}

// ---------------- aggregation: one wave per node ----------------
// rows: f16 [NN][DIM]. If APPLY: row value = relu(rows*s + t) (BN affine fused).
template <bool APPLY>
__global__ __launch_bounds__(256) void k_agg(const _Float16* __restrict__ rows,
                                             const float* __restrict__ ss,
                                             const float* __restrict__ Cl,
                                             const int* __restrict__ row_ptr,
                                             const int* __restrict__ recs,
                                             _Float16* __restrict__ aggh) {
    int node = (blockIdx.x * blockDim.x + threadIdx.x) >> 6;
    int lane = threadIdx.x & 63;
    if (node >= NN) return;
    int c = lane * 4;
    float s0 = 1.f, s1 = 1.f, s2 = 1.f, s3 = 1.f, t0 = 0.f, t1 = 0.f, t2 = 0.f, t3 = 0.f;
    if (APPLY) {
        s0 = ss[c]; s1 = ss[c + 1]; s2 = ss[c + 2]; s3 = ss[c + 3];
        t0 = ss[DIM + c]; t1 = ss[DIM + c + 1]; t2 = ss[DIM + c + 2]; t3 = ss[DIM + c + 3];
    }
    float4 cv0 = *(const float4*)(Cl + c);   // self-loop attr = (0,0)
    half4v sv = *(const half4v*)(rows + (size_t)node * DIM + c);
    float ax, ay, az, aw;
    if (APPLY) {
        ax = fmaxf((float)sv.x * s0 + t0, 0.f) + cv0.x;
        ay = fmaxf((float)sv.y * s1 + t1, 0.f) + cv0.y;
        az = fmaxf((float)sv.z * s2 + t2, 0.f) + cv0.z;
        aw = fmaxf((float)sv.w * s3 + t3, 0.f) + cv0.w;
    } else {
        ax = (float)sv.x + cv0.x;
        ay = (float)sv.y + cv0.y;
        az = (float)sv.z + cv0.z;
        aw = (float)sv.w + cv0.w;
    }
    int e0 = row_ptr[node], e1 = row_ptr[node + 1];
    for (int e = e0; e < e1; ++e) {
        int rec = recs[e];
        int src = rec & 0xFFFFF;
        int attr = rec >> 20;
        half4v hv = *(const half4v*)(rows + (size_t)src * DIM + c);
        float4 cv = *(const float4*)(Cl + (size_t)attr * DIM + c);
        if (APPLY) {
            ax += fmaxf((float)hv.x * s0 + t0, 0.f) + cv.x;
            ay += fmaxf((float)hv.y * s1 + t1, 0.f) + cv.y;
            az += fmaxf((float)hv.z * s2 + t2, 0.f) + cv.z;
            aw += fmaxf((float)hv.w * s3 + t3, 0.f) + cv.w;
        } else {
            ax += (float)hv.x + cv.x;
            ay += (float)hv.y + cv.y;
            az += (float)hv.z + cv.z;
            aw += (float)hv.w + cv.w;
        }
    }
    half4v o;
    o.x = (_Float16)ax; o.y = (_Float16)ay; o.z = (_Float16)az; o.w = (_Float16)aw;
    *(half4v*)(aggh + (size_t)node * DIM + c) = o;
}

// ---------------- fused MLP: Z = (relu(A@W1+b1))@W2 + b2, + BN stats ----------------
// 64-row tile per block, 256 threads (4 waves). LDS: A-chunk 16KB + H 64KB = 80KB
// -> 2 blocks/CU. Stage-1: wave computes 64rows x 128cols (acc 128 VGPR), A-frags
// from LDS (XOR-swizzled), B-frags (W1t) direct from L2. H round-trips through LDS
// (C-layout -> A-layout transform). Stage-2: wave computes 64rows x 64cols.
// Epilogue: bias+stats, z through LDS transpose -> coalesced dwordx4 stores.
__global__ __launch_bounds__(256, 2) void k_mlp(const _Float16* __restrict__ A,
                                                const _Float16* __restrict__ W1t,
                                                const float* __restrict__ b1,
                                                const _Float16* __restrict__ W2t,
                                                const float* __restrict__ b2,
                                                _Float16* __restrict__ Z,
                                                float* __restrict__ stats, int M) {
    __shared__ _Float16 ldsA[64 * 128];   // 16 KB (A k-chunk, swizzled)
    __shared__ _Float16 ldsH[64 * 512];   // 64 KB (H tile; reused as Z tile)
    int tid = threadIdx.x;
    int w = tid >> 6, lane = tid & 63;
    int lm = lane & 15, lg = lane >> 4;
    int row0 = blockIdx.x * 64;

    // ---------- stage 1 ----------
    float4v acc1[4][8];
    const float4v zero = {0.f, 0.f, 0.f, 0.f};
#pragma unroll
    for (int i = 0; i < 4; ++i)
#pragma unroll
        for (int j = 0; j < 8; ++j) acc1[i][j] = zero;

#pragma unroll
    for (int kc = 0; kc < 2; ++kc) {
        // stage A chunk: 64 rows x 128 k. Wave stages rows w*16..w*16+15.
        {
            int srow = lane >> 4;      // 0..3
            int slot = lane & 15;      // 16B slot within 128-f16 row
#pragma unroll
            for (int j = 0; j < 4; ++j) {
                int cr = w * 16 + j * 4 + srow;
                int gr = min(row0 + cr, M - 1);
                int gk = kc * 128 + ((slot ^ (cr & 7)) * 8);
                gl_lds16(A + (size_t)gr * DIM + gk, ldsA + (w * 16 + j * 4) * 128);
            }
        }
        __syncthreads();
#pragma unroll
        for (int qq = 0; qq < 4; ++qq) {
            half8 bf[8];
#pragma unroll
            for (int nt = 0; nt < 8; ++nt) {
                int n = w * 128 + nt * 16 + lm;
                bf[nt] = *(const half8*)(W1t + (size_t)n * DIM + kc * 128 + qq * 32 + lg * 8);
            }
            half8 af[4];
#pragma unroll
            for (int mt = 0; mt < 4; ++mt) {
                int m = mt * 16 + lm;
                int slot = qq * 4 + lg;
                af[mt] = *(const half8*)(ldsA + m * 128 + ((slot ^ (m & 7)) * 8));
            }
#pragma unroll
            for (int mt = 0; mt < 4; ++mt)
#pragma unroll
                for (int nt = 0; nt < 8; ++nt)
                    acc1[mt][nt] = __builtin_amdgcn_mfma_f32_16x16x32_f16(af[mt], bf[nt],
                                                                          acc1[mt][nt], 0, 0, 0);
        }
        __syncthreads();
    }

    // H (relu) -> ldsH, f16, XOR-swizzled by row (C-layout: col=lm, row=lg*4+r)
#pragma unroll
    for (int nt = 0; nt < 8; ++nt) {
        int col = w * 128 + nt * 16 + lm;
        float bv = b1[col];
        int cs = col >> 3, ci = col & 7;
#pragma unroll
        for (int mt = 0; mt < 4; ++mt)
#pragma unroll
            for (int r = 0; r < 4; ++r) {
                int row = mt * 16 + lg * 4 + r;
                float v = fmaxf(acc1[mt][nt][r] + bv, 0.f);
                ldsH[row * 512 + ((cs ^ (row & 7)) << 3) + ci] = (_Float16)v;
            }
    }
    __syncthreads();

    // ---------- stage 2 ----------
    float4v acc2[4][4];
#pragma unroll
    for (int i = 0; i < 4; ++i)
#pragma unroll
        for (int j = 0; j < 4; ++j) acc2[i][j] = zero;

#pragma unroll
    for (int q = 0; q < 16; ++q) {
        half8 bf[4];
#pragma unroll
        for (int nt = 0; nt < 4; ++nt) {
            int n = w * 64 + nt * 16 + lm;
            bf[nt] = *(const half8*)(W2t + (size_t)n * HID + q * 32 + lg * 8);
        }
        half8 af[4];
#pragma unroll
        for (int mt = 0; mt < 4; ++mt) {
            int m = mt * 16 + lm;
            int slot = q * 4 + lg;                 // 0..63
            af[mt] = *(const half8*)(ldsH + m * 512 + ((slot ^ (m & 7)) << 3));
        }
#pragma unroll
        for (int mt = 0; mt < 4; ++mt)
#pragma unroll
            for (int nt = 0; nt < 4; ++nt)
                acc2[mt][nt] = __builtin_amdgcn_mfma_f32_16x16x32_f16(af[mt], bf[nt],
                                                                      acc2[mt][nt], 0, 0, 0);
    }
    __syncthreads();   // ldsH free -> reuse as Z tile

    // ---------- epilogue: bias + stats + z via LDS transpose ----------
    _Float16* ldsZ = ldsH;   // 64 x 256 f16, swizzled
    float psum[4], psq[4];
#pragma unroll
    for (int nt = 0; nt < 4; ++nt) { psum[nt] = 0.f; psq[nt] = 0.f; }
#pragma unroll
    for (int nt = 0; nt < 4; ++nt) {
        int col = w * 64 + nt * 16 + lm;
        float bv = b2[col];
        int cs = col >> 3, ci = col & 7;
#pragma unroll
        for (int mt = 0; mt < 4; ++mt)
#pragma unroll
            for (int r = 0; r < 4; ++r) {
                int row = mt * 16 + lg * 4 + r;
                float v = acc2[mt][nt][r] + bv;
                if (row0 + row < M) {
                    psum[nt] += v;
                    psq[nt] += v * v;
                }
                ldsZ[row * 256 + ((cs ^ (row & 7)) << 3) + ci] = (_Float16)v;
            }
    }
#pragma unroll
    for (int nt = 0; nt < 4; ++nt) {
        psum[nt] += __shfl_xor(psum[nt], 16);
        psum[nt] += __shfl_xor(psum[nt], 32);
        psq[nt] += __shfl_xor(psq[nt], 16);
        psq[nt] += __shfl_xor(psq[nt], 32);
    }
    if (lg == 0) {
#pragma unroll
        for (int nt = 0; nt < 4; ++nt) {
            int ch = w * 64 + nt * 16 + lm;
            atomicAdd(&stats[ch], psum[nt]);
            atomicAdd(&stats[DIM + ch], psq[nt]);
        }
    }
    __syncthreads();
    // coalesced store: 2048 16B-slots, thread t -> slots t, t+256, ...
#pragma unroll
    for (int i = 0; i < 8; ++i) {
        int s = i * 256 + tid;
        int row = s >> 5, c16 = s & 31;
        if (row0 + row < M) {
            half8 v = *(const half8*)(ldsZ + row * 256 + ((c16 ^ (row & 7)) << 3));
            *(half8*)(Z + (size_t)(row0 + row) * DIM + c16 * 8) = v;
        }
    }
}

// ---------------- BatchNorm finalize (also re-zeros stats) + final output ----------------
__global__ void k_bnfin(float* __restrict__ stats, const float* __restrict__ gamma,
                        const float* __restrict__ beta, float* __restrict__ ss) {
    int c = threadIdx.x;
    float mu = stats[c] * (1.0f / NN);
    float var = stats[DIM + c] * (1.0f / NN) - mu * mu;
    float sc = gamma[c] / sqrtf(var + BN_EPS);
    ss[c] = sc;
    ss[DIM + c] = beta[c] - mu * sc;
    stats[c] = 0.f;
    stats[DIM + c] = 0.f;
}

__global__ void k_out(const _Float16* __restrict__ z, const float* __restrict__ ss,
                      float* __restrict__ out) {
    int i = blockIdx.x * blockDim.x + threadIdx.x;
    if (i >= NN * DIM / 4) return;
    int c4 = (i & (DIM / 4 - 1)) * 4;
    half4v v = ((const half4v*)z)[i];
    float4 o;
    o.x = (float)v.x * ss[c4] + ss[DIM + c4];
    o.y = (float)v.y * ss[c4 + 1] + ss[DIM + c4 + 1];
    o.z = (float)v.z * ss[c4 + 2] + ss[DIM + c4 + 2];
    o.w = (float)v.w * ss[c4 + 3] + ss[DIM + c4 + 3];
    ((float4*)out)[i] = o;
}

// ---------------- host launcher ----------------
extern "C" void kernel_launch(void* const* d_in, const int* in_sizes, int n_in,
                              void* d_out, int out_size, void* d_ws, size_t ws_size,
                              hipStream_t stream) {
    const float* x = (const float*)d_in[0];
    const int* ei = (const int*)d_in[1];
    const int* ea = (const int*)d_in[2];
    const float* W1 = (const float*)d_in[4];
    const float* b1 = (const float*)d_in[5];
    const float* W2 = (const float*)d_in[6];
    const float* b2 = (const float*)d_in[7];
    const float* E1 = (const float*)d_in[8];
    const float* E2 = (const float*)d_in[9];
    const float* gamma = (const float*)d_in[10];
    const float* beta = (const float*)d_in[11];
    float* out = (float*)d_out;

    char* w = (char*)d_ws;
    _Float16* xh = (_Float16*)w;   w += (size_t)NN * DIM * 2;
    _Float16* z = (_Float16*)w;    w += (size_t)NN * DIM * 2;
    _Float16* aggh = (_Float16*)w; w += (size_t)NN * DIM * 2;
    _Float16* W1t = (_Float16*)w;  w += (size_t)NL * DIM * HID * 2;
    _Float16* W2t = (_Float16*)w;  w += (size_t)NL * HID * DIM * 2;
    float* Ctab = (float*)w;       w += (size_t)NL * 9 * DIM * 4;
    float* stats = (float*)w;      w += 2 * DIM * 4;
    float* ss = (float*)w;         w += 2 * DIM * 4;
    int* row_ptr = (int*)w;        w += (size_t)(NN + 2) * 4;
    int* counts = (int*)w;         w += (size_t)NN * 4;
    int* cursor = (int*)w;         w += (size_t)NN * 4;
    int* bsum = (int*)w;           w += 256 * 4;
    int* bofs = (int*)w;           w += 256 * 4;
    int* recs = (int*)w;           w += (size_t)NE * 4;

    // setup: f16 x, edge-combo tables, CSR by dst, transposed f16 weights
    k_zero<<<(NN + 255) / 256, 256, 0, stream>>>(counts, NN);
    k_zero<<<2, 256, 0, stream>>>((int*)stats, 2 * DIM);
    k_x2h<<<(NN * DIM / 4 + 255) / 256, 256, 0, stream>>>(x, xh);
    k_ctab<<<NL * 9, 256, 0, stream>>>(E1, E2, Ctab);
    k_hist<<<(NE + 255) / 256, 256, 0, stream>>>(ei, counts);
    k_bsum<<<NB_SCAN, 256, 0, stream>>>(counts, bsum);
    k_bscan<<<1, 256, 0, stream>>>(bsum, bofs);
    k_scatterptr<<<NB_SCAN, 256, 0, stream>>>(counts, bofs, row_ptr, cursor);
    k_fill<<<(NE + 255) / 256, 256, 0, stream>>>(ei, ea, cursor, recs);
    {
        dim3 b(32, 8);
        dim3 g1(HID / 32, DIM / 32, NL);
        k_wt<<<g1, b, 0, stream>>>(W1, W1t, DIM, HID);
        dim3 g2(DIM / 32, HID / 32, NL);
        k_wt<<<g2, b, 0, stream>>>(W2, W2t, HID, DIM);
    }

    for (int l = 0; l < NL; ++l) {
        const float* Cl = Ctab + (size_t)l * 9 * DIM;
        if (l == 0)
            k_agg<false><<<(NN + 3) / 4, 256, 0, stream>>>(xh, ss, Cl, row_ptr, recs, aggh);
        else
            k_agg<true><<<(NN + 3) / 4, 256, 0, stream>>>(z, ss, Cl, row_ptr, recs, aggh);

        k_mlp<<<(NN + 63) / 64, 256, 0, stream>>>(aggh, W1t + (size_t)l * DIM * HID,
                                                  b1 + (size_t)l * HID,
                                                  W2t + (size_t)l * HID * DIM,
                                                  b2 + (size_t)l * DIM, z, stats, NN);

        k_bnfin<<<1, 256, 0, stream>>>(stats, gamma + (size_t)l * DIM, beta + (size_t)l * DIM, ss);
    }
    k_out<<<(NN * DIM / 4 + 255) / 256, 256, 0, stream>>>(z, ss, out);
}